// Round 6
// baseline (5904.726 us; speedup 1.0000x reference)
//
#include <hip/hip_runtime.h>
#include <hip/hip_bf16.h>
#include <math.h>

// Model constants (fixed by the reference)
#define D_MODEL 768
#define N_LAYER 4
#define D_STATE 16
#define D_CONV  4
#define DT_RANK 48
#define D_INNER 1536
#define B_SZ    2
#define L_SEQ   1024
#define N_MELS  80
#define ROWS    (B_SZ * L_SEQ)   // 2048

#define NBLK    1024              // co-resident: LDS 27.6KB(<=5/CU), VGPR<=128(4/CU)
#define SMEMB   27648             // max phase LDS: gemm64 (9216+18432)

typedef __bf16 bf16x8 __attribute__((ext_vector_type(8)));
typedef unsigned short u16x8 __attribute__((ext_vector_type(8)));
typedef float  f32x4  __attribute__((ext_vector_type(4)));

// raw transcendentals (1 ulp; v_exp_f32 computes 2^x)
__device__ __forceinline__ float fast_exp2(float x) {
    float r; asm("v_exp_f32 %0, %1" : "=v"(r) : "v"(x)); return r;
}
__device__ __forceinline__ float fast_exp(float x) {
    return fast_exp2(x * 1.44269504f);
}
__device__ __forceinline__ float fast_rcp(float x) {
    float r; asm("v_rcp_f32 %0, %1" : "=v"(r) : "v"(x)); return r;
}
__device__ __forceinline__ float silu_f(float v) {
    return v * fast_rcp(1.0f + fast_exp(-v));
}
__device__ __forceinline__ float softplus_f(float v) {
    return fmaxf(v, 0.0f) + log1pf(expf(-fabsf(v)));
}
__device__ __forceinline__ unsigned short f2bf(float f) {
    unsigned int u = __float_as_uint(f);
    unsigned int r = (u + 0x7FFFu + ((u >> 16) & 1u)) >> 16;
    return (unsigned short)r;
}
__device__ __forceinline__ float bf2f(unsigned short v) {
    return __uint_as_float(((unsigned int)v) << 16);
}

// ---- device-scope grid barrier (monotonic ticket; blocks co-resident) ----
// Release on arrive makes this block's writes visible (agent scope = L2
// writeback); acquire on the observing load invalidates L1/XCD-L2 so all
// threads of the block (same CU) read fresh data after __syncthreads.
__device__ __forceinline__ void gsync(unsigned int* bar, unsigned int nb) {
    __syncthreads();
    if (threadIdx.x == 0) {
        unsigned int t = __hip_atomic_fetch_add(bar, 1u, __ATOMIC_ACQ_REL,
                                                __HIP_MEMORY_SCOPE_AGENT);
        unsigned int target = (t / nb + 1u) * nb;
        while (__hip_atomic_load(bar, __ATOMIC_ACQUIRE,
                                 __HIP_MEMORY_SCOPE_AGENT) < target)
            __builtin_amdgcn_s_sleep(2);
    }
    __syncthreads();
}

// ---------------- rmsnorm row -> bf16 ----------------
__device__ __forceinline__ void d_rms(int row, int tid, char* smem,
        const float* __restrict__ x, const float* __restrict__ w,
        unsigned short* __restrict__ hb) {
    float* ws = (float*)smem;
    const float* xr = x + (size_t)row * D_MODEL;
    float p = 0.f;
    for (int c = tid; c < D_MODEL; c += 256) { float v = xr[c]; p = fmaf(v, v, p); }
    for (int off = 32; off >= 1; off >>= 1) p += __shfl_down(p, off, 64);
    int lane = tid & 63, wv = tid >> 6;
    if (lane == 0) ws[wv] = p;
    __syncthreads();
    if (tid == 0) ws[0] = ws[0] + ws[1] + ws[2] + ws[3];
    __syncthreads();
    float scale = 1.0f / sqrtf(ws[0] / (float)D_MODEL + 1e-5f);
    for (int c = tid; c < D_MODEL; c += 256)
        hb[(size_t)row * D_MODEL + c] = f2bf(xr[c] * scale * w[c]);
}

// ---------------- per-layer weight prep job ----------------
__device__ void d_prep(int bx, int tid, char* smem,
        const float* __restrict__ in_wi, const float* __restrict__ out_wi,
        const float* __restrict__ xp_wi, const float* __restrict__ dt_wi,
        unsigned short* __restrict__ wt_in, unsigned short* __restrict__ wt_out,
        unsigned short* __restrict__ xpT, unsigned short* __restrict__ dtwT) {
    float (*t)[33] = (float(*)[33])smem;
    if (bx < 3456) {
        const float* src; unsigned short* dst; int R, C, cy, cx;
        if (bx < 2304) {
            src = in_wi; dst = wt_in; R = D_MODEL; C = 2 * D_INNER;
            cy = bx / 96; cx = bx - cy * 96;
        } else {
            int tt = bx - 2304;
            src = out_wi; dst = wt_out; R = D_INNER; C = D_MODEL;
            cy = tt / 24; cx = tt - cy * 24;
        }
        int tx = tid & 31, ty = tid >> 5;
        int r0 = cy * 32, c0 = cx * 32;
#pragma unroll
        for (int i = 0; i < 4; i++)
            t[ty + i * 8][tx] = src[(size_t)(r0 + ty + i * 8) * C + c0 + tx];
        __syncthreads();
#pragma unroll
        for (int i = 0; i < 4; i++)
            dst[(size_t)(c0 + ty + i * 8) * R + r0 + tx] = f2bf(t[tx][ty + i * 8]);
    } else {
        int i = (bx - 3456) * 256 + tid;
        if (i < 80 * D_INNER) {
            int c = i / D_INNER, r = i - c * D_INNER;
            xpT[i] = f2bf(xp_wi[(size_t)r * 80 + c]);
        } else {
            int i2 = i - 80 * D_INNER;   // < 1536*64
            int c = i2 >> 6, r = i2 & 63;
            dtwT[i2] = (r < DT_RANK) ? f2bf(dt_wi[(size_t)r * D_INNER + c])
                                     : (unsigned short)0;
        }
    }
}

// ---------------- bf16 MFMA GEMM tile 64x128, BK=64 (in_proj) ------------
__device__ void d_gemm64(const unsigned short* __restrict__ A,
                         const unsigned short* __restrict__ BT,
                         unsigned short* __restrict__ Cb,
                         int K, int ldc, int cx, int ry, int tid, char* smem) {
    unsigned short (*As)[72] = (unsigned short(*)[72])smem;
    unsigned short (*Bs)[72] = (unsigned short(*)[72])(smem + 9216);
    int row0 = ry * 64, col0 = cx * 128;
    int wave = tid >> 6, lane = tid & 63;
    int wr = (wave >> 1) * 32, wc = (wave & 1) * 64;
    int lm = lane & 15, lq = lane >> 4;
    int sr = tid >> 3, seg = tid & 7;
    const unsigned short* Ap0 = A  + (size_t)(row0 + sr) * K + seg * 8;
    const unsigned short* Ap1 = A  + (size_t)(row0 + 32 + sr) * K + seg * 8;
    const unsigned short* Bp0 = BT + (size_t)(col0 + sr) * K + seg * 8;
    const unsigned short* Bp1 = BT + (size_t)(col0 + 32 + sr) * K + seg * 8;
    const unsigned short* Bp2 = BT + (size_t)(col0 + 64 + sr) * K + seg * 8;
    const unsigned short* Bp3 = BT + (size_t)(col0 + 96 + sr) * K + seg * 8;
    f32x4 acc[2][4] = {};
    bf16x8 pa0 = *(const bf16x8*)Ap0;
    bf16x8 pa1 = *(const bf16x8*)Ap1;
    bf16x8 pb0 = *(const bf16x8*)Bp0;
    bf16x8 pb1 = *(const bf16x8*)Bp1;
    bf16x8 pb2 = *(const bf16x8*)Bp2;
    bf16x8 pb3 = *(const bf16x8*)Bp3;
    *(bf16x8*)&As[sr][seg * 8]      = pa0;
    *(bf16x8*)&As[32 + sr][seg * 8] = pa1;
    *(bf16x8*)&Bs[sr][seg * 8]      = pb0;
    *(bf16x8*)&Bs[32 + sr][seg * 8] = pb1;
    *(bf16x8*)&Bs[64 + sr][seg * 8] = pb2;
    *(bf16x8*)&Bs[96 + sr][seg * 8] = pb3;
    for (int k0 = 0; k0 < K; k0 += 64) {
        __syncthreads();
        bool more = (k0 + 64 < K);
        if (more) {
            pa0 = *(const bf16x8*)(Ap0 + k0 + 64);
            pa1 = *(const bf16x8*)(Ap1 + k0 + 64);
            pb0 = *(const bf16x8*)(Bp0 + k0 + 64);
            pb1 = *(const bf16x8*)(Bp1 + k0 + 64);
            pb2 = *(const bf16x8*)(Bp2 + k0 + 64);
            pb3 = *(const bf16x8*)(Bp3 + k0 + 64);
        }
#pragma unroll
        for (int ks = 0; ks < 2; ks++) {
            bf16x8 af[2], bfr[4];
#pragma unroll
            for (int i = 0; i < 2; i++)
                af[i] = *(const bf16x8*)&As[wr + i * 16 + lm][ks * 32 + lq * 8];
#pragma unroll
            for (int j = 0; j < 4; j++)
                bfr[j] = *(const bf16x8*)&Bs[wc + j * 16 + lm][ks * 32 + lq * 8];
#pragma unroll
            for (int i = 0; i < 2; i++)
#pragma unroll
                for (int j = 0; j < 4; j++)
                    acc[i][j] = __builtin_amdgcn_mfma_f32_16x16x32_bf16(af[i], bfr[j], acc[i][j], 0, 0, 0);
        }
        __syncthreads();
        if (more) {
            *(bf16x8*)&As[sr][seg * 8]      = pa0;
            *(bf16x8*)&As[32 + sr][seg * 8] = pa1;
            *(bf16x8*)&Bs[sr][seg * 8]      = pb0;
            *(bf16x8*)&Bs[32 + sr][seg * 8] = pb1;
            *(bf16x8*)&Bs[64 + sr][seg * 8] = pb2;
            *(bf16x8*)&Bs[96 + sr][seg * 8] = pb3;
        }
    }
#pragma unroll
    for (int i = 0; i < 2; i++) {
#pragma unroll
        for (int ii = 0; ii < 4; ii++) {
            int row = row0 + wr + i * 16 + lq * 4 + ii;
#pragma unroll
            for (int j = 0; j < 4; j++) {
                int col = col0 + wc + j * 16 + lm;
                Cb[(size_t)row * ldc + col] = f2bf(acc[i][j][ii]);
            }
        }
    }
}

// ---------------- bf16 MFMA GEMM tile 32x128, BK=64, fp32 out ------------
// AT=false: A row-major [M][K] (delta). AT=true: A is [K][M] (ygT) —
// staging transposes via 8x ds_write_b16 into padded As.
template<bool AT>
__device__ void d_gemm32(const unsigned short* __restrict__ A,
                         const unsigned short* __restrict__ BT,
                         const float* __restrict__ bias,
                         const float* __restrict__ resid,
                         float* __restrict__ Cf,
                         int M, int K, int ldc, int act, int bias_mode,
                         int cx, int ry, int tid, char* smem) {
    unsigned short (*As)[72] = (unsigned short(*)[72])smem;
    unsigned short (*Bs)[72] = (unsigned short(*)[72])(smem + 4608);
    int row0 = ry * 32, col0 = cx * 128;
    int wave = tid >> 6, lane = tid & 63;
    int wc = wave * 32;
    int lm = lane & 15, lq = lane >> 4;
    int sr = tid >> 3, seg = tid & 7;
    const unsigned short* Bp0 = BT + (size_t)(col0 + sr) * K + seg * 8;
    const unsigned short* Bp1 = BT + (size_t)(col0 + 32 + sr) * K + seg * 8;
    const unsigned short* Bp2 = BT + (size_t)(col0 + 64 + sr) * K + seg * 8;
    const unsigned short* Bp3 = BT + (size_t)(col0 + 96 + sr) * K + seg * 8;
    int akk = tid >> 2, arc = (tid & 3) * 8;
    const unsigned short* ApT = AT ? (A + (size_t)akk * M + row0 + arc) : nullptr;
    const unsigned short* Ap  = AT ? nullptr : (A + (size_t)(row0 + sr) * K + seg * 8);
    f32x4 acc[2][2] = {};
    u16x8 pa;
    if (AT) pa = *(const u16x8*)ApT;
    else    pa = *(const u16x8*)Ap;
    bf16x8 pb0 = *(const bf16x8*)Bp0;
    bf16x8 pb1 = *(const bf16x8*)Bp1;
    bf16x8 pb2 = *(const bf16x8*)Bp2;
    bf16x8 pb3 = *(const bf16x8*)Bp3;
    if (AT) {
#pragma unroll
        for (int j = 0; j < 8; j++) As[arc + j][akk] = pa[j];
    } else {
        *(u16x8*)&As[sr][seg * 8] = pa;
    }
    *(bf16x8*)&Bs[sr][seg * 8]      = pb0;
    *(bf16x8*)&Bs[32 + sr][seg * 8] = pb1;
    *(bf16x8*)&Bs[64 + sr][seg * 8] = pb2;
    *(bf16x8*)&Bs[96 + sr][seg * 8] = pb3;
    for (int k0 = 0; k0 < K; k0 += 64) {
        __syncthreads();
        bool more = (k0 + 64 < K);
        if (more) {
            if (AT) pa = *(const u16x8*)(ApT + (size_t)(k0 + 64) * M);
            else    pa = *(const u16x8*)(Ap + k0 + 64);
            pb0 = *(const bf16x8*)(Bp0 + k0 + 64);
            pb1 = *(const bf16x8*)(Bp1 + k0 + 64);
            pb2 = *(const bf16x8*)(Bp2 + k0 + 64);
            pb3 = *(const bf16x8*)(Bp3 + k0 + 64);
        }
#pragma unroll
        for (int ks = 0; ks < 2; ks++) {
            bf16x8 af[2], bfr[2];
#pragma unroll
            for (int i = 0; i < 2; i++)
                af[i] = *(const bf16x8*)&As[i * 16 + lm][ks * 32 + lq * 8];
#pragma unroll
            for (int j = 0; j < 2; j++)
                bfr[j] = *(const bf16x8*)&Bs[wc + j * 16 + lm][ks * 32 + lq * 8];
#pragma unroll
            for (int i = 0; i < 2; i++)
#pragma unroll
                for (int j = 0; j < 2; j++)
                    acc[i][j] = __builtin_amdgcn_mfma_f32_16x16x32_bf16(af[i], bfr[j], acc[i][j], 0, 0, 0);
        }
        __syncthreads();
        if (more) {
            if (AT) {
#pragma unroll
                for (int j = 0; j < 8; j++) As[arc + j][akk] = pa[j];
            } else {
                *(u16x8*)&As[sr][seg * 8] = pa;
            }
            *(bf16x8*)&Bs[sr][seg * 8]      = pb0;
            *(bf16x8*)&Bs[32 + sr][seg * 8] = pb1;
            *(bf16x8*)&Bs[64 + sr][seg * 8] = pb2;
            *(bf16x8*)&Bs[96 + sr][seg * 8] = pb3;
        }
    }
#pragma unroll
    for (int i = 0; i < 2; i++) {
#pragma unroll
        for (int ii = 0; ii < 4; ii++) {
            int row = row0 + i * 16 + lq * 4 + ii;
#pragma unroll
            for (int j = 0; j < 2; j++) {
                int col = col0 + wc + j * 16 + lm;
                float v = acc[i][j][ii];
                if (bias) v += bias[bias_mode ? row : col];
                if (act == 1) v = softplus_f(v);
                if (resid) v += resid[(size_t)row * ldc + col];
                Cf[(size_t)row * ldc + col] = v;
            }
        }
    }
}

// ---------------- skinny split-K bf16 MFMA -> private partials -----------
// AT=false: A bf16 row-major [M][K] (head). AT=true: A f32 [K][M] (uT).
template<bool AT>
__device__ void d_skinny(const unsigned short* __restrict__ A,
                         const float* __restrict__ AfT,
                         const unsigned short* __restrict__ BT,
                         float* __restrict__ part,
                         int M, int K, int kchunk, int rb, int ks, int tid, char* smem) {
    constexpr int N = 80, NT = 5;
    unsigned short (*As)[40] = (unsigned short(*)[40])smem;
    unsigned short (*Bs)[40] = (unsigned short(*)[40])(smem + 10240);
    int row0 = rb * 128;
    int kb = ks * kchunk, ke = kb + kchunk;
    float* myout = part + (size_t)ks * M * N;
    int wave = tid >> 6, lane = tid & 63;
    int wr = wave * 32;
    int lm = lane & 15, lq = lane >> 4;
    int ar0 = tid >> 2, ar1 = (tid + 256) >> 2, aseg = tid & 3;
    const unsigned short* Ap0 = AT ? nullptr : (A + (size_t)(row0 + ar0) * K + aseg * 8);
    const unsigned short* Ap1 = AT ? nullptr : (A + (size_t)(row0 + ar1) * K + aseg * 8);
    int srl = tid >> 5, src4 = (tid & 31) * 4;
    const float* Af0 = AT ? (AfT + (size_t)(srl + 0) * M + row0 + src4) : nullptr;
    const float* Af1 = AT ? (AfT + (size_t)(srl + 8) * M + row0 + src4) : nullptr;
    const float* Af2 = AT ? (AfT + (size_t)(srl + 16) * M + row0 + src4) : nullptr;
    const float* Af3 = AT ? (AfT + (size_t)(srl + 24) * M + row0 + src4) : nullptr;
    const unsigned short* Bp0 = BT + (size_t)ar0 * K + aseg * 8;
    const unsigned short* Bp1 = BT + (size_t)ar1 * K + aseg * 8;
    bool haveB1 = (tid < 64);
    f32x4 acc[2][NT] = {};
    bf16x8 pa0, pa1;
    f32x4 qa0, qa1, qa2, qa3;
    if (AT) {
        qa0 = *(const f32x4*)(Af0 + (size_t)kb * M);
        qa1 = *(const f32x4*)(Af1 + (size_t)kb * M);
        qa2 = *(const f32x4*)(Af2 + (size_t)kb * M);
        qa3 = *(const f32x4*)(Af3 + (size_t)kb * M);
    } else {
        pa0 = *(const bf16x8*)(Ap0 + kb);
        pa1 = *(const bf16x8*)(Ap1 + kb);
    }
    bf16x8 pb0 = *(const bf16x8*)(Bp0 + kb);
    bf16x8 pb1 = {};
    if (haveB1) pb1 = *(const bf16x8*)(Bp1 + kb);
    if (AT) {
#pragma unroll
        for (int e = 0; e < 4; e++) {
            As[src4 + e][srl]      = f2bf(qa0[e]);
            As[src4 + e][srl + 8]  = f2bf(qa1[e]);
            As[src4 + e][srl + 16] = f2bf(qa2[e]);
            As[src4 + e][srl + 24] = f2bf(qa3[e]);
        }
    } else {
        *(bf16x8*)&As[ar0][aseg * 8] = pa0;
        *(bf16x8*)&As[ar1][aseg * 8] = pa1;
    }
    *(bf16x8*)&Bs[ar0][aseg * 8] = pb0;
    if (haveB1) *(bf16x8*)&Bs[ar1][aseg * 8] = pb1;
    for (int k0 = kb; k0 < ke; k0 += 32) {
        __syncthreads();
        bool more = (k0 + 32 < ke);
        if (more) {
            if (AT) {
                qa0 = *(const f32x4*)(Af0 + (size_t)(k0 + 32) * M);
                qa1 = *(const f32x4*)(Af1 + (size_t)(k0 + 32) * M);
                qa2 = *(const f32x4*)(Af2 + (size_t)(k0 + 32) * M);
                qa3 = *(const f32x4*)(Af3 + (size_t)(k0 + 32) * M);
            } else {
                pa0 = *(const bf16x8*)(Ap0 + k0 + 32);
                pa1 = *(const bf16x8*)(Ap1 + k0 + 32);
            }
            pb0 = *(const bf16x8*)(Bp0 + k0 + 32);
            if (haveB1) pb1 = *(const bf16x8*)(Bp1 + k0 + 32);
        }
        bf16x8 af[2], bfr[NT];
#pragma unroll
        for (int i = 0; i < 2; i++) af[i] = *(const bf16x8*)&As[wr + i * 16 + lm][lq * 8];
#pragma unroll
        for (int j = 0; j < NT; j++) bfr[j] = *(const bf16x8*)&Bs[j * 16 + lm][lq * 8];
#pragma unroll
        for (int i = 0; i < 2; i++)
#pragma unroll
            for (int j = 0; j < NT; j++)
                acc[i][j] = __builtin_amdgcn_mfma_f32_16x16x32_bf16(af[i], bfr[j], acc[i][j], 0, 0, 0);
        __syncthreads();
        if (more) {
            if (AT) {
#pragma unroll
                for (int e = 0; e < 4; e++) {
                    As[src4 + e][srl]      = f2bf(qa0[e]);
                    As[src4 + e][srl + 8]  = f2bf(qa1[e]);
                    As[src4 + e][srl + 16] = f2bf(qa2[e]);
                    As[src4 + e][srl + 24] = f2bf(qa3[e]);
                }
            } else {
                *(bf16x8*)&As[ar0][aseg * 8] = pa0;
                *(bf16x8*)&As[ar1][aseg * 8] = pa1;
            }
            *(bf16x8*)&Bs[ar0][aseg * 8] = pb0;
            if (haveB1) *(bf16x8*)&Bs[ar1][aseg * 8] = pb1;
        }
    }
#pragma unroll
    for (int i = 0; i < 2; i++) {
#pragma unroll
        for (int ii = 0; ii < 4; ii++) {
            int row = row0 + wr + i * 16 + lq * 4 + ii;
#pragma unroll
            for (int j = 0; j < NT; j++) {
                int col = j * 16 + lm;
                myout[(size_t)row * N + col] = acc[i][j][ii];
            }
        }
    }
}

// ---------------- tiled causal conv (k=4) + silu -> uT -------------------
__device__ void d_conv(int b, int tid, char* smem,
        const unsigned short* __restrict__ xzb,
        const float* __restrict__ cw, const float* __restrict__ cb,
        float* __restrict__ uT) {
    unsigned short (*s_xz)[66] = (unsigned short(*)[66])smem;
    float (*us)[65] = (float(*)[65])(smem + 8848);
    int d0 = (b % 24) * 64, r0 = (b / 24) * 64;
    bool atStart = (r0 & (L_SEQ - 1)) == 0;
    for (int idx = tid; idx < 67 * 64; idx += 256) {
        int rr = idx >> 6, cc2 = idx & 63;
        unsigned short v = 0;
        if (rr >= 3 || !atStart)
            v = xzb[(size_t)(r0 - 3 + rr) * (2 * D_INNER) + d0 + cc2];
        s_xz[rr][cc2] = v;
    }
    __syncthreads();
    int cc = tid & 63, ty = tid >> 6;
    const float* wp = cw + (size_t)(d0 + cc) * D_CONV;
    float w0 = wp[0], w1 = wp[1], w2 = wp[2], w3 = wp[3];
    float bb = cb[d0 + cc];
    for (int rr = ty; rr < 64; rr += 4) {
        float s = bb;
        s = fmaf(bf2f(s_xz[rr + 0][cc]), w0, s);
        s = fmaf(bf2f(s_xz[rr + 1][cc]), w1, s);
        s = fmaf(bf2f(s_xz[rr + 2][cc]), w2, s);
        s = fmaf(bf2f(s_xz[rr + 3][cc]), w3, s);
        us[rr][cc] = silu_f(s);
    }
    __syncthreads();
    int tx = tid & 63, dy = tid >> 6;
    for (int dd = dy; dd < 64; dd += 4)
        uT[(size_t)(d0 + dd) * ROWS + r0 + tx] = us[tx][dd];
}

// ---------------- z half -> resT transpose (64x64 tile) ------------------
__device__ void d_ztr(int zt, int tid, char* smem,
        const unsigned short* __restrict__ xzb,
        unsigned short* __restrict__ resT) {
    unsigned short (*s_zt)[66] = (unsigned short(*)[66])smem;
    int dt = zt >> 5, rt = zt & 31;
    int d0 = dt * 64, r0 = rt * 64;
    for (int idx = tid; idx < 64 * 64; idx += 256) {
        int rr = idx >> 6, cc = idx & 63;
        s_zt[rr][cc] = xzb[(size_t)(r0 + rr) * (2 * D_INNER) + D_INNER + d0 + cc];
    }
    __syncthreads();
    int tx = tid & 63, dy = tid >> 6;
    for (int dd = dy; dd < 64; dd += 4)
        resT[(size_t)(d0 + dd) * ROWS + r0 + tx] = s_zt[tx][dd];
}

// ---------------- chunk-parallel selective scan, adaptive re-chunk -------
__device__ void d_scan(int bd, int tid, char* smem,
        const float* __restrict__ deltaT, const float* __restrict__ uT,
        const float* __restrict__ xdbl, const unsigned short* __restrict__ resT,
        const float* __restrict__ A_li, const float* __restrict__ Dpi,
        unsigned short* __restrict__ ygT) {
    float2* s_du = (float2*)smem;                    // (L_SEQ+16)*8 = 8320
    float (*cs1)[17] = (float(*)[17])(smem + 8320);  // 1088
    float (*cs2)[17] = (float(*)[17])(smem + 9408);  // 1088
    float* gmv = (float*)(smem + 10496);             // 64
    int n = tid & 15, c = tid >> 4;
    int b = bd / D_INNER, d = bd - b * D_INNER;
    int row0 = b * L_SEQ;
    float a2 = -fast_exp(A_li[d * D_STATE + n]) * 1.44269504f;
    float Dd = Dpi[d];
    const float* dptr = deltaT + (size_t)d * ROWS + row0;
    const float* uptr = uT + (size_t)d * ROWS + row0;
    for (int e = tid; e < L_SEQ; e += 256)
        s_du[e + (e >> 6)] = make_float2(dptr[e], uptr[e]);
    __syncthreads();
    {
        int l0 = c * 64, sb = l0 + c;
        bool notfirst = (c != 0);
        float sum = 0.f;
#pragma unroll 8
        for (int j = 0; j < 64; j++) {
            float dA = fmaxf(s_du[sb + j].x * a2, -28.8539008f);
            if (j > 0 || notfirst) sum += dA;
        }
        cs1[n][c] = sum;
    }
    __syncthreads();
    float cbase = 0.f;
    for (int cc = 0; cc < c; cc++) cbase += cs1[n][cc];
    float gm = cbase;
    gm = fmaxf(gm, __shfl_xor(gm, 1, 16));
    gm = fmaxf(gm, __shfl_xor(gm, 2, 16));
    gm = fmaxf(gm, __shfl_xor(gm, 4, 16));
    gm = fmaxf(gm, __shfl_xor(gm, 8, 16));
    if (n == 0) gmv[c] = gm;
    __syncthreads();
    int lc = 16;
    for (int cc = 1; cc < 16; cc++)
        if (gmv[cc] <= -150.0f) { lc = cc; break; }
    int clen = lc * 4;
    int l0b = c * clen;
    int lend = lc * 64;
    {
        float sum = 0.f;
        for (int j = 0; j < clen; j++) {
            int l = l0b + j;
            float dA = fmaxf(s_du[l + (l >> 6)].x * a2, -28.8539008f);
            if (l > 0) sum += dA;
        }
        cs1[n][c] = sum;
    }
    __syncthreads();
    float cbase_b = 0.f;
    for (int cc = 0; cc < c; cc++) cbase_b += cs1[n][cc];
    const float* xBbase = xdbl + (size_t)row0 * 80 + DT_RANK + n;
    {
        float Cacc = cbase_b, psum = 0.f;
        for (int j = 0; j < clen; j++) {
            int l = l0b + j;
            float2 du = s_du[l + (l >> 6)];
            float dA = fmaxf(du.x * a2, -28.8539008f);
            if (l > 0) Cacc += dA;
            float S = fast_exp2(Cacc);
            float r = fast_rcp(S + 1e-12f);
            psum = fmaf(du.x * du.y * xBbase[l * 80], r, psum);
        }
        cs2[n][c] = psum;
    }
    __syncthreads();
    float pbase = 0.f;
    for (int cc = 0; cc < c; cc++) pbase += cs2[n][cc];
    {
        float Cacc = cbase_b, P = pbase;
        for (int j = 0; j < clen; j++) {
            int l = l0b + j;
            float2 du = s_du[l + (l >> 6)];
            float dA = fmaxf(du.x * a2, -28.8539008f);
            if (l > 0) Cacc += dA;
            float S = fast_exp2(Cacc);
            float r = fast_rcp(S + 1e-12f);
            P = fmaf(du.x * du.y * xBbase[l * 80], r, P);
            float contrib = P * S * xBbase[l * 80 + 16];
            contrib += __shfl_xor(contrib, 1, 16);
            contrib += __shfl_xor(contrib, 2, 16);
            contrib += __shfl_xor(contrib, 4, 16);
            contrib += __shfl_xor(contrib, 8, 16);
            if (n == 0) s_du[l + (l >> 6)].x = contrib + du.y * Dd;
        }
    }
    __syncthreads();
    const unsigned short* rptr = resT + (size_t)d * ROWS + row0;
    unsigned short* yout = ygT + (size_t)d * ROWS + row0;
    for (int e = tid; e < L_SEQ; e += 256) {
        float2 v = s_du[e + (e >> 6)];
        float y = (e < lend) ? v.x : v.y * Dd;
        float res = bf2f(rptr[e]);
        yout[e] = f2bf(y * silu_f(res));
    }
}

// ---------------- megakernel args ----------------
struct MegaArgs {
    const int* ids; const float* emb; const float* rms_w; const float* in_w;
    const float* conv_w; const float* conv_b; const float* xp_w;
    const float* dt_w; const float* dt_b; const float* A_log; const float* Dp;
    const float* out_w; const float* nf_w; const float* head_w;
    float* out; char* ws; unsigned int* bar;
};

// ---------------- the whole forward as one persistent kernel -------------
__global__ __launch_bounds__(256, 4) void mega(MegaArgs a) {
    __shared__ __align__(16) char smem[SMEMB];
    int tid = threadIdx.x;
    unsigned int nb = gridDim.x;
    char* base = a.ws;
    float*          x      = (float*)(base + 0);
    unsigned short* hb     = (unsigned short*)(base + 6291456);
    unsigned short* xzb    = (unsigned short*)(base + 9437184);
    unsigned short* ygT    = (unsigned short*)(base + 9437184);   // aliases xzb lo
    float*          uT     = (float*)(base + 22020096);
    float*          xdbl   = (float*)(base + 34603008);
    unsigned short* xdblb  = (unsigned short*)(base + 35258368);
    float*          part   = (float*)(base + 35520512);           // 24 splits
    float*          deltaT = (float*)(base + 41811968);
    unsigned short* resT   = (unsigned short*)(base + 54394880);
    unsigned short* wt_in  = (unsigned short*)(base + 60686336);
    unsigned short* wt_out = (unsigned short*)(base + 65404928);
    unsigned short* xpT    = (unsigned short*)(base + 67764224);
    unsigned short* dtwT   = (unsigned short*)(base + 68009984);
    unsigned short* headT  = (unsigned short*)(base + 68206592);
    unsigned int* bar = a.bar;

    // P0: embedding gather + head-weight transpose
    {
        int nth = (int)nb * 256;
        int tot = ROWS * D_MODEL + N_MELS * D_MODEL;
        for (int i = blockIdx.x * 256 + tid; i < tot; i += nth) {
            if (i < ROWS * D_MODEL) {
                int r = i / D_MODEL, cc = i - r * D_MODEL;
                x[i] = a.emb[(size_t)a.ids[r] * D_MODEL + cc];
            } else {
                int j = i - ROWS * D_MODEL;
                int cc = j / D_MODEL, r = j - cc * D_MODEL;
                headT[j] = f2bf(a.head_w[(size_t)r * N_MELS + cc]);
            }
        }
    }
    gsync(bar, nb);

    for (int L = 0; L < N_LAYER; ++L) {
        const float* in_wi   = a.in_w  + (size_t)L * D_MODEL * 2 * D_INNER;
        const float* conv_wi = a.conv_w + (size_t)L * D_INNER * D_CONV;
        const float* conv_bi = a.conv_b + (size_t)L * D_INNER;
        const float* xp_wi   = a.xp_w  + (size_t)L * D_INNER * (DT_RANK + 2 * D_STATE);
        const float* dt_wi   = a.dt_w  + (size_t)L * DT_RANK * D_INNER;
        const float* dt_bi   = a.dt_b  + (size_t)L * D_INNER;
        const float* A_li    = a.A_log + (size_t)L * D_INNER * D_STATE;
        const float* Dpi     = a.Dp    + (size_t)L * D_INNER;
        const float* out_wi  = a.out_w + (size_t)L * D_INNER * D_MODEL;
        const float* rms_wi  = a.rms_w + (size_t)L * D_MODEL;

        // P1: weight prep (4320) + rmsnorm (2048)
        for (int j = blockIdx.x; j < 4320 + ROWS; j += nb) {
            __syncthreads();
            if (j < 4320)
                d_prep(j, tid, smem, in_wi, out_wi, xp_wi, dt_wi,
                       wt_in, wt_out, xpT, dtwT);
            else
                d_rms(j - 4320, tid, smem, x, rms_wi, hb);
        }
        gsync(bar, nb);
        // P2: xz = h @ in_proj_w  (768 tile jobs of 64x128)
        for (int j = blockIdx.x; j < 768; j += nb) {
            __syncthreads();
            d_gemm64(hb, wt_in, xzb, D_MODEL, 2 * D_INNER, j % 24, j / 24, tid, smem);
        }
        gsync(bar, nb);
        // P3: conv+silu -> uT (768) + z -> resT transpose (768)
        for (int j = blockIdx.x; j < 1536; j += nb) {
            __syncthreads();
            if (j < 768) d_conv(j, tid, smem, xzb, conv_wi, conv_bi, uT);
            else         d_ztr(j - 768, tid, smem, xzb, resT);
        }
        gsync(bar, nb);
        // P4: x_dbl = u @ x_proj_w, split-24 (384 jobs)
        for (int j = blockIdx.x; j < 384; j += nb) {
            __syncthreads();
            d_skinny<true>(nullptr, uT, xpT, part, ROWS, D_INNER, D_INNER / 24,
                           j % 16, j / 16, tid, smem);
        }
        gsync(bar, nb);
        // P5: split-K reduce + bf16 cvt (640 jobs)
        for (int j = blockIdx.x; j < 640; j += nb) {
            int i = j * 256 + tid;
            if (i < ROWS * 80) {
                float s = 0.f;
                for (int k = 0; k < 24; k++) s += part[(size_t)k * ROWS * 80 + i];
                xdbl[i] = s;
                int r = i / 80, cc = i - r * 80;
                if (cc < DT_RANK) xdblb[r * 64 + cc] = f2bf(s);
                else if (cc >= 64) xdblb[r * 64 + cc - 16] = 0;
            }
        }
        gsync(bar, nb);
        // P6: deltaT = softplus(dt_w^T @ x_dbl^T + dt_b)  (768 jobs)
        for (int j = blockIdx.x; j < 768; j += nb) {
            __syncthreads();
            d_gemm32<false>(dtwT, xdblb, dt_bi, nullptr, deltaT,
                            D_INNER, 64, ROWS, 1, 1, j % 16, j / 16, tid, smem);
        }
        gsync(bar, nb);
        // P7: scan + gate -> ygT  (3072 jobs)
        for (int j = blockIdx.x; j < B_SZ * D_INNER; j += nb) {
            __syncthreads();
            d_scan(j, tid, smem, deltaT, uT, xdbl, resT, A_li, Dpi, ygT);
        }
        gsync(bar, nb);
        // P8: x = yg @ out_proj_w + x  (384 jobs)
        for (int j = blockIdx.x; j < 384; j += nb) {
            __syncthreads();
            d_gemm32<true>(ygT, wt_out, nullptr, x, x,
                           ROWS, D_INNER, D_MODEL, 0, 0, j % 6, j / 6, tid, smem);
        }
        gsync(bar, nb);
    }

    // P9: final rmsnorm (2048 jobs)
    for (int j = blockIdx.x; j < ROWS; j += nb) {
        __syncthreads();
        d_rms(j, tid, smem, x, a.nf_w, hb);
    }
    gsync(bar, nb);
    // P10: head split-24 (384 jobs)
    for (int j = blockIdx.x; j < 384; j += nb) {
        __syncthreads();
        d_skinny<false>(hb, nullptr, headT, part, ROWS, D_MODEL, D_MODEL / 24,
                        j % 16, j / 16, tid, smem);
    }
    gsync(bar, nb);
    // P11: head reduce (640 jobs)
    for (int j = blockIdx.x; j < 640; j += nb) {
        int i = j * 256 + tid;
        if (i < ROWS * N_MELS) {
            float s = 0.f;
            for (int k = 0; k < 24; k++) s += part[(size_t)k * ROWS * N_MELS + i];
            a.out[i] = s;
        }
    }
}

extern "C" void kernel_launch(void* const* d_in, const int* in_sizes, int n_in,
                              void* d_out, int out_size, void* d_ws, size_t ws_size,
                              hipStream_t stream) {
    char* base = (char*)d_ws;
    // barrier counter just past the 68,329,472-byte buffer region (d_ws is
    // 256 MiB — the harness re-poison fills 262144 KB — so this is in-bounds).
    unsigned int* bar = (unsigned int*)(base + 68329472);
    hipMemsetAsync(bar, 0, sizeof(unsigned int), stream);

    MegaArgs a;
    a.ids    = (const int*)d_in[0];
    a.emb    = (const float*)d_in[1];
    a.rms_w  = (const float*)d_in[2];
    a.in_w   = (const float*)d_in[3];
    a.conv_w = (const float*)d_in[4];
    a.conv_b = (const float*)d_in[5];
    a.xp_w   = (const float*)d_in[6];
    a.dt_w   = (const float*)d_in[7];
    a.dt_b   = (const float*)d_in[8];
    a.A_log  = (const float*)d_in[9];
    a.Dp     = (const float*)d_in[10];
    a.out_w  = (const float*)d_in[11];
    a.nf_w   = (const float*)d_in[12];
    a.head_w = (const float*)d_in[13];
    a.out    = (float*)d_out;
    a.ws     = base;
    a.bar    = bar;

    mega<<<NBLK, 256, 0, stream>>>(a);
}

// Round 7
// 687.943 us; speedup vs baseline: 8.5832x; 8.5832x over previous
//
#include <hip/hip_runtime.h>
#include <hip/hip_bf16.h>
#include <math.h>

// Model constants (fixed by the reference)
#define D_MODEL 768
#define N_LAYER 4
#define D_STATE 16
#define D_CONV  4
#define DT_RANK 48
#define D_INNER 1536
#define B_SZ    2
#define L_SEQ   1024
#define N_MELS  80
#define ROWS    (B_SZ * L_SEQ)   // 2048
#define NSPLIT  24

typedef __bf16 bf16x8 __attribute__((ext_vector_type(8)));
typedef unsigned short u16x8 __attribute__((ext_vector_type(8)));
typedef float  f32x4  __attribute__((ext_vector_type(4)));

// raw transcendentals (1 ulp; v_exp_f32 computes 2^x)
__device__ __forceinline__ float fast_exp2(float x) {
    float r; asm("v_exp_f32 %0, %1" : "=v"(r) : "v"(x)); return r;
}
__device__ __forceinline__ float fast_exp(float x) {
    return fast_exp2(x * 1.44269504f);
}
__device__ __forceinline__ float fast_rcp(float x) {
    float r; asm("v_rcp_f32 %0, %1" : "=v"(r) : "v"(x)); return r;
}
__device__ __forceinline__ float silu_f(float v) {
    return v * fast_rcp(1.0f + fast_exp(-v));
}
__device__ __forceinline__ float softplus_f(float v) {
    return fmaxf(v, 0.0f) + log1pf(expf(-fabsf(v)));
}
__device__ __forceinline__ unsigned short f2bf(float f) {
    unsigned int u = __float_as_uint(f);
    unsigned int r = (u + 0x7FFFu + ((u >> 16) & 1u)) >> 16;
    return (unsigned short)r;
}
__device__ __forceinline__ float bf2f(unsigned short v) {
    return __uint_as_float(((unsigned int)v) << 16);
}

// ---------------- embedding gather + head-weight transpose (merged) ------
__global__ void embed_head_kernel(const int* __restrict__ ids,
                                  const float* __restrict__ emb,
                                  float* __restrict__ x,
                                  const float* __restrict__ head_w,
                                  unsigned short* __restrict__ headT) {
    int i = blockIdx.x * 256 + threadIdx.x;
    if (i < ROWS * D_MODEL) {
        int r = i / D_MODEL, c = i - r * D_MODEL;
        x[i] = emb[(size_t)ids[r] * D_MODEL + c];
    } else {
        int j = i - ROWS * D_MODEL;
        if (j < N_MELS * D_MODEL) {
            int c = j / D_MODEL, r = j - c * D_MODEL;   // headT[c][r]
            headT[j] = f2bf(head_w[(size_t)r * N_MELS + c]);
        }
    }
}

// ---------------- rmsnorm -> bf16 (final norm) ----------------
__global__ void rmsnorm_kernel(const float* __restrict__ x,
                               const float* __restrict__ w,
                               unsigned short* __restrict__ hb) {
    int row = blockIdx.x;
    const float* xr = x + (size_t)row * D_MODEL;
    int tid = threadIdx.x;
    float p = 0.f;
    for (int c = tid; c < D_MODEL; c += 256) { float v = xr[c]; p = fmaf(v, v, p); }
    for (int off = 32; off >= 1; off >>= 1) p += __shfl_down(p, off, 64);
    __shared__ float ws[4];
    int lane = tid & 63, wv = tid >> 6;
    if (lane == 0) ws[wv] = p;
    __syncthreads();
    if (tid == 0) ws[0] = ws[0] + ws[1] + ws[2] + ws[3];
    __syncthreads();
    float scale = 1.0f / sqrtf(ws[0] / (float)D_MODEL + 1e-5f);
    for (int c = tid; c < D_MODEL; c += 256)
        hb[(size_t)row * D_MODEL + c] = f2bf(xr[c] * scale * w[c]);
}

// -------- per-layer weight prep + rmsnorm, co-dispatched (R5-verified) ---
// blocks [0,4320): weight prep; [4320,6368): rmsnorm rows. Independent.
__global__ void prep_rms_kernel(const float* __restrict__ in_wi,
                                const float* __restrict__ out_wi,
                                const float* __restrict__ xp_wi,
                                const float* __restrict__ dt_wi,
                                unsigned short* __restrict__ wt_in,
                                unsigned short* __restrict__ wt_out,
                                unsigned short* __restrict__ xpT,
                                unsigned short* __restrict__ dtwT,
                                const float* __restrict__ x,
                                const float* __restrict__ rms_wi,
                                unsigned short* __restrict__ hb) {
    __shared__ float t[32][33];
    __shared__ float ws[4];
    int bx = blockIdx.x;
    int tid = threadIdx.x;
    if (bx >= 4320) {
        int row = bx - 4320;
        const float* xr = x + (size_t)row * D_MODEL;
        float p = 0.f;
        for (int c = tid; c < D_MODEL; c += 256) { float v = xr[c]; p = fmaf(v, v, p); }
        for (int off = 32; off >= 1; off >>= 1) p += __shfl_down(p, off, 64);
        int lane = tid & 63, wv = tid >> 6;
        if (lane == 0) ws[wv] = p;
        __syncthreads();
        if (tid == 0) ws[0] = ws[0] + ws[1] + ws[2] + ws[3];
        __syncthreads();
        float scale = 1.0f / sqrtf(ws[0] / (float)D_MODEL + 1e-5f);
        for (int c = tid; c < D_MODEL; c += 256)
            hb[(size_t)row * D_MODEL + c] = f2bf(xr[c] * scale * rms_wi[c]);
        return;
    }
    if (bx < 3456) {
        const float* src; unsigned short* dst; int R, C, cy, cx;
        if (bx < 2304) {
            src = in_wi; dst = wt_in; R = D_MODEL; C = 2 * D_INNER;
            cy = bx / 96; cx = bx - cy * 96;
        } else {
            int tt = bx - 2304;
            src = out_wi; dst = wt_out; R = D_INNER; C = D_MODEL;
            cy = tt / 24; cx = tt - cy * 24;
        }
        int tx = tid & 31, ty = tid >> 5;
        int r0 = cy * 32, c0 = cx * 32;
#pragma unroll
        for (int i = 0; i < 4; i++)
            t[ty + i * 8][tx] = src[(size_t)(r0 + ty + i * 8) * C + c0 + tx];
        __syncthreads();
#pragma unroll
        for (int i = 0; i < 4; i++)
            dst[(size_t)(c0 + ty + i * 8) * R + r0 + tx] = f2bf(t[tx][ty + i * 8]);
    } else {
        int i = (bx - 3456) * 256 + tid;
        if (i < 80 * D_INNER) {
            int c = i / D_INNER, r = i - c * D_INNER;
            xpT[i] = f2bf(xp_wi[(size_t)r * 80 + c]);
        } else {
            int i2 = i - 80 * D_INNER;   // < 1536*64
            int c = i2 >> 6, r = i2 & 63;
            dtwT[i2] = (r < DT_RANK) ? f2bf(dt_wi[(size_t)r * D_INNER + c])
                                     : (unsigned short)0;
        }
    }
}

// ---------------- split-K reduce (+ fused bf16 [ROWS][64] cvt) -----------
__global__ void reduce_cvt_kernel(const float* __restrict__ part,
                                  float* __restrict__ xdbl,
                                  unsigned short* __restrict__ xdblb,
                                  int nsplit) {
    int i = blockIdx.x * 256 + threadIdx.x;
    if (i >= ROWS * 80) return;
    float s = 0.f;
    for (int k = 0; k < nsplit; k++) s += part[(size_t)k * ROWS * 80 + i];
    xdbl[i] = s;
    int r = i / 80, c = i - r * 80;
    if (c < DT_RANK) xdblb[r * 64 + c] = f2bf(s);
    else if (c >= 64) xdblb[r * 64 + c - 16] = 0;
}

// ---------------- plain split-K reduce (head) ----------------------------
__global__ void reduce_split_kernel(const float* __restrict__ part,
                                    float* __restrict__ dst,
                                    int MN, int nsplit) {
    int i = blockIdx.x * 256 + threadIdx.x;
    if (i >= MN) return;
    float s = 0.f;
    for (int k = 0; k < nsplit; k++) s += part[(size_t)k * MN + i];
    dst[i] = s;
}

// ---------------- bf16 MFMA GEMM, 64x128 tile, BK=64, reg-pipelined ------
// grid (N/128, M/64). R2-proven structure: padded LDS (no bank conflicts),
// reg prefetch across MFMA, 2 barriers per 64-wide K-step.
__global__ __launch_bounds__(256) void mfma_gemm64(
        const unsigned short* __restrict__ A,
        const unsigned short* __restrict__ BT,
        const float* __restrict__ bias, const float* __restrict__ resid,
        float* __restrict__ Cf, unsigned short* __restrict__ Cb,
        int M, int N, int K, int ldc, int act, int bias_mode) {
    __shared__ unsigned short As[64][72];
    __shared__ unsigned short Bs[128][72];
    int tid = threadIdx.x;
    int row0 = blockIdx.y * 64, col0 = blockIdx.x * 128;
    int wave = tid >> 6, lane = tid & 63;
    int wr = (wave >> 1) * 32, wc = (wave & 1) * 64;
    int lm = lane & 15, lq = lane >> 4;
    int sr = tid >> 3, seg = tid & 7;        // 32 rows/round, 8x16B segs/row
    const unsigned short* Ap0 = A  + (size_t)(row0 + sr) * K + seg * 8;
    const unsigned short* Ap1 = A  + (size_t)(row0 + 32 + sr) * K + seg * 8;
    const unsigned short* Bp0 = BT + (size_t)(col0 + sr) * K + seg * 8;
    const unsigned short* Bp1 = BT + (size_t)(col0 + 32 + sr) * K + seg * 8;
    const unsigned short* Bp2 = BT + (size_t)(col0 + 64 + sr) * K + seg * 8;
    const unsigned short* Bp3 = BT + (size_t)(col0 + 96 + sr) * K + seg * 8;
    f32x4 acc[2][4] = {};
    bf16x8 pa0 = *(const bf16x8*)Ap0;
    bf16x8 pa1 = *(const bf16x8*)Ap1;
    bf16x8 pb0 = *(const bf16x8*)Bp0;
    bf16x8 pb1 = *(const bf16x8*)Bp1;
    bf16x8 pb2 = *(const bf16x8*)Bp2;
    bf16x8 pb3 = *(const bf16x8*)Bp3;
    *(bf16x8*)&As[sr][seg * 8]      = pa0;
    *(bf16x8*)&As[32 + sr][seg * 8] = pa1;
    *(bf16x8*)&Bs[sr][seg * 8]      = pb0;
    *(bf16x8*)&Bs[32 + sr][seg * 8] = pb1;
    *(bf16x8*)&Bs[64 + sr][seg * 8] = pb2;
    *(bf16x8*)&Bs[96 + sr][seg * 8] = pb3;
    for (int k0 = 0; k0 < K; k0 += 64) {
        __syncthreads();
        bool more = (k0 + 64 < K);
        if (more) {
            pa0 = *(const bf16x8*)(Ap0 + k0 + 64);
            pa1 = *(const bf16x8*)(Ap1 + k0 + 64);
            pb0 = *(const bf16x8*)(Bp0 + k0 + 64);
            pb1 = *(const bf16x8*)(Bp1 + k0 + 64);
            pb2 = *(const bf16x8*)(Bp2 + k0 + 64);
            pb3 = *(const bf16x8*)(Bp3 + k0 + 64);
        }
#pragma unroll
        for (int ks = 0; ks < 2; ks++) {
            bf16x8 af[2], bfr[4];
#pragma unroll
            for (int i = 0; i < 2; i++)
                af[i] = *(const bf16x8*)&As[wr + i * 16 + lm][ks * 32 + lq * 8];
#pragma unroll
            for (int j = 0; j < 4; j++)
                bfr[j] = *(const bf16x8*)&Bs[wc + j * 16 + lm][ks * 32 + lq * 8];
#pragma unroll
            for (int i = 0; i < 2; i++)
#pragma unroll
                for (int j = 0; j < 4; j++)
                    acc[i][j] = __builtin_amdgcn_mfma_f32_16x16x32_bf16(af[i], bfr[j], acc[i][j], 0, 0, 0);
        }
        __syncthreads();
        if (more) {
            *(bf16x8*)&As[sr][seg * 8]      = pa0;
            *(bf16x8*)&As[32 + sr][seg * 8] = pa1;
            *(bf16x8*)&Bs[sr][seg * 8]      = pb0;
            *(bf16x8*)&Bs[32 + sr][seg * 8] = pb1;
            *(bf16x8*)&Bs[64 + sr][seg * 8] = pb2;
            *(bf16x8*)&Bs[96 + sr][seg * 8] = pb3;
        }
    }
#pragma unroll
    for (int i = 0; i < 2; i++) {
#pragma unroll
        for (int ii = 0; ii < 4; ii++) {
            int row = row0 + wr + i * 16 + lq * 4 + ii;
#pragma unroll
            for (int j = 0; j < 4; j++) {
                int col = col0 + wc + j * 16 + lm;
                float v = acc[i][j][ii];
                if (bias) v += bias[bias_mode ? row : col];
                if (act == 1) v = softplus_f(v);
                if (resid) v += resid[(size_t)row * ldc + col];
                if (Cf) Cf[(size_t)row * ldc + col] = v;
                else    Cb[(size_t)row * ldc + col] = f2bf(v);
            }
        }
    }
}

// ---------------- bf16 MFMA GEMM, 32x128, BK=64, templated A layout ------
// AT=false: A row-major [M][K] (delta GEMM). AT=true: A is [K][M] (ygT
// from the scan) — staging transposes via 8x ds_write_b16 into padded As.
template<bool AT>
__global__ __launch_bounds__(256) void mfma_gemm32(
        const unsigned short* __restrict__ A,
        const unsigned short* __restrict__ BT,
        const float* __restrict__ bias, const float* __restrict__ resid,
        float* __restrict__ Cf, unsigned short* __restrict__ Cb,
        int M, int N, int K, int ldc, int act, int bias_mode) {
    __shared__ unsigned short As[32][72];
    __shared__ unsigned short Bs[128][72];
    int tid = threadIdx.x;
    int row0 = blockIdx.y * 32, col0 = blockIdx.x * 128;
    int wave = tid >> 6, lane = tid & 63;
    int wc = wave * 32;
    int lm = lane & 15, lq = lane >> 4;
    int sr = tid >> 3, seg = tid & 7;
    const unsigned short* Bp0 = BT + (size_t)(col0 + sr) * K + seg * 8;
    const unsigned short* Bp1 = BT + (size_t)(col0 + 32 + sr) * K + seg * 8;
    const unsigned short* Bp2 = BT + (size_t)(col0 + 64 + sr) * K + seg * 8;
    const unsigned short* Bp3 = BT + (size_t)(col0 + 96 + sr) * K + seg * 8;
    // A staging addresses
    int akk = tid >> 2, arc = (tid & 3) * 8;          // AT: kk row, r col
    const unsigned short* ApT = AT ? (A + (size_t)akk * M + row0 + arc) : nullptr;
    const unsigned short* Ap  = AT ? nullptr : (A + (size_t)(row0 + sr) * K + seg * 8);
    f32x4 acc[2][2] = {};
    u16x8 pa;
    if (AT) pa = *(const u16x8*)ApT;
    else    pa = *(const u16x8*)Ap;
    bf16x8 pb0 = *(const bf16x8*)Bp0;
    bf16x8 pb1 = *(const bf16x8*)Bp1;
    bf16x8 pb2 = *(const bf16x8*)Bp2;
    bf16x8 pb3 = *(const bf16x8*)Bp3;
    if (AT) {
#pragma unroll
        for (int j = 0; j < 8; j++) As[arc + j][akk] = pa[j];
    } else {
        *(u16x8*)&As[sr][seg * 8] = pa;
    }
    *(bf16x8*)&Bs[sr][seg * 8]      = pb0;
    *(bf16x8*)&Bs[32 + sr][seg * 8] = pb1;
    *(bf16x8*)&Bs[64 + sr][seg * 8] = pb2;
    *(bf16x8*)&Bs[96 + sr][seg * 8] = pb3;
    for (int k0 = 0; k0 < K; k0 += 64) {
        __syncthreads();
        bool more = (k0 + 64 < K);
        if (more) {
            if (AT) pa = *(const u16x8*)(ApT + (size_t)(k0 + 64) * M);
            else    pa = *(const u16x8*)(Ap + k0 + 64);
            pb0 = *(const bf16x8*)(Bp0 + k0 + 64);
            pb1 = *(const bf16x8*)(Bp1 + k0 + 64);
            pb2 = *(const bf16x8*)(Bp2 + k0 + 64);
            pb3 = *(const bf16x8*)(Bp3 + k0 + 64);
        }
#pragma unroll
        for (int ks = 0; ks < 2; ks++) {
            bf16x8 af[2], bfr[2];
#pragma unroll
            for (int i = 0; i < 2; i++)
                af[i] = *(const bf16x8*)&As[i * 16 + lm][ks * 32 + lq * 8];
#pragma unroll
            for (int j = 0; j < 2; j++)
                bfr[j] = *(const bf16x8*)&Bs[wc + j * 16 + lm][ks * 32 + lq * 8];
#pragma unroll
            for (int i = 0; i < 2; i++)
#pragma unroll
                for (int j = 0; j < 2; j++)
                    acc[i][j] = __builtin_amdgcn_mfma_f32_16x16x32_bf16(af[i], bfr[j], acc[i][j], 0, 0, 0);
        }
        __syncthreads();
        if (more) {
            if (AT) {
#pragma unroll
                for (int j = 0; j < 8; j++) As[arc + j][akk] = pa[j];
            } else {
                *(u16x8*)&As[sr][seg * 8] = pa;
            }
            *(bf16x8*)&Bs[sr][seg * 8]      = pb0;
            *(bf16x8*)&Bs[32 + sr][seg * 8] = pb1;
            *(bf16x8*)&Bs[64 + sr][seg * 8] = pb2;
            *(bf16x8*)&Bs[96 + sr][seg * 8] = pb3;
        }
    }
#pragma unroll
    for (int i = 0; i < 2; i++) {
#pragma unroll
        for (int ii = 0; ii < 4; ii++) {
            int row = row0 + i * 16 + lq * 4 + ii;
#pragma unroll
            for (int j = 0; j < 2; j++) {
                int col = col0 + wc + j * 16 + lm;
                float v = acc[i][j][ii];
                if (bias) v += bias[bias_mode ? row : col];
                if (act == 1) v = softplus_f(v);
                if (resid) v += resid[(size_t)row * ldc + col];
                if (Cf) Cf[(size_t)row * ldc + col] = v;
                else    Cb[(size_t)row * ldc + col] = f2bf(v);
            }
        }
    }
}

// ---------------- skinny split-K bf16 MFMA -> private partials -----------
// N fixed at 80 (NT=5 compile-time). grid (M/128, nsplit).
// AT=false: A bf16 row-major [M][K] (head). AT=true: A f32 [K][M] (uT).
template<bool AT>
__global__ __launch_bounds__(256) void mfma_skinny(
        const unsigned short* __restrict__ A,
        const float* __restrict__ AfT,
        const unsigned short* __restrict__ BT,
        float* __restrict__ part,
        int M, int K, int kchunk) {
    constexpr int N = 80, NT = 5;
    __shared__ unsigned short As[128][40];
    __shared__ unsigned short Bs[80][40];
    int tid = threadIdx.x;
    int row0 = blockIdx.x * 128;
    int kb = blockIdx.y * kchunk, ke = kb + kchunk;
    float* myout = part + (size_t)blockIdx.y * M * N;
    int wave = tid >> 6, lane = tid & 63;
    int wr = wave * 32;
    int lm = lane & 15, lq = lane >> 4;
    int ar0 = tid >> 2, ar1 = (tid + 256) >> 2, aseg = tid & 3;
    const unsigned short* Ap0 = AT ? nullptr : (A + (size_t)(row0 + ar0) * K + aseg * 8);
    const unsigned short* Ap1 = AT ? nullptr : (A + (size_t)(row0 + ar1) * K + aseg * 8);
    int srl = tid >> 5, src4 = (tid & 31) * 4;
    const float* Af0 = AT ? (AfT + (size_t)(srl + 0) * M + row0 + src4) : nullptr;
    const float* Af1 = AT ? (AfT + (size_t)(srl + 8) * M + row0 + src4) : nullptr;
    const float* Af2 = AT ? (AfT + (size_t)(srl + 16) * M + row0 + src4) : nullptr;
    const float* Af3 = AT ? (AfT + (size_t)(srl + 24) * M + row0 + src4) : nullptr;
    const unsigned short* Bp0 = BT + (size_t)ar0 * K + aseg * 8;   // tid < 320 always
    const unsigned short* Bp1 = BT + (size_t)ar1 * K + aseg * 8;   // valid only tid < 64
    bool haveB1 = (tid < 64);
    f32x4 acc[2][NT] = {};
    bf16x8 pa0, pa1;
    f32x4 qa0, qa1, qa2, qa3;
    if (AT) {
        qa0 = *(const f32x4*)(Af0 + (size_t)kb * M);
        qa1 = *(const f32x4*)(Af1 + (size_t)kb * M);
        qa2 = *(const f32x4*)(Af2 + (size_t)kb * M);
        qa3 = *(const f32x4*)(Af3 + (size_t)kb * M);
    } else {
        pa0 = *(const bf16x8*)(Ap0 + kb);
        pa1 = *(const bf16x8*)(Ap1 + kb);
    }
    bf16x8 pb0 = *(const bf16x8*)(Bp0 + kb);
    bf16x8 pb1 = {};
    if (haveB1) pb1 = *(const bf16x8*)(Bp1 + kb);
    if (AT) {
#pragma unroll
        for (int e = 0; e < 4; e++) {
            As[src4 + e][srl]      = f2bf(qa0[e]);
            As[src4 + e][srl + 8]  = f2bf(qa1[e]);
            As[src4 + e][srl + 16] = f2bf(qa2[e]);
            As[src4 + e][srl + 24] = f2bf(qa3[e]);
        }
    } else {
        *(bf16x8*)&As[ar0][aseg * 8] = pa0;
        *(bf16x8*)&As[ar1][aseg * 8] = pa1;
    }
    *(bf16x8*)&Bs[ar0][aseg * 8] = pb0;
    if (haveB1) *(bf16x8*)&Bs[ar1][aseg * 8] = pb1;
    for (int k0 = kb; k0 < ke; k0 += 32) {
        __syncthreads();
        bool more = (k0 + 32 < ke);
        if (more) {
            if (AT) {
                qa0 = *(const f32x4*)(Af0 + (size_t)(k0 + 32) * M);
                qa1 = *(const f32x4*)(Af1 + (size_t)(k0 + 32) * M);
                qa2 = *(const f32x4*)(Af2 + (size_t)(k0 + 32) * M);
                qa3 = *(const f32x4*)(Af3 + (size_t)(k0 + 32) * M);
            } else {
                pa0 = *(const bf16x8*)(Ap0 + k0 + 32);
                pa1 = *(const bf16x8*)(Ap1 + k0 + 32);
            }
            pb0 = *(const bf16x8*)(Bp0 + k0 + 32);
            if (haveB1) pb1 = *(const bf16x8*)(Bp1 + k0 + 32);
        }
        bf16x8 af[2], bfr[NT];
#pragma unroll
        for (int i = 0; i < 2; i++) af[i] = *(const bf16x8*)&As[wr + i * 16 + lm][lq * 8];
#pragma unroll
        for (int j = 0; j < NT; j++) bfr[j] = *(const bf16x8*)&Bs[j * 16 + lm][lq * 8];
#pragma unroll
        for (int i = 0; i < 2; i++)
#pragma unroll
            for (int j = 0; j < NT; j++)
                acc[i][j] = __builtin_amdgcn_mfma_f32_16x16x32_bf16(af[i], bfr[j], acc[i][j], 0, 0, 0);
        __syncthreads();
        if (more) {
            if (AT) {
#pragma unroll
                for (int e = 0; e < 4; e++) {
                    As[src4 + e][srl]      = f2bf(qa0[e]);
                    As[src4 + e][srl + 8]  = f2bf(qa1[e]);
                    As[src4 + e][srl + 16] = f2bf(qa2[e]);
                    As[src4 + e][srl + 24] = f2bf(qa3[e]);
                }
            } else {
                *(bf16x8*)&As[ar0][aseg * 8] = pa0;
                *(bf16x8*)&As[ar1][aseg * 8] = pa1;
            }
            *(bf16x8*)&Bs[ar0][aseg * 8] = pb0;
            if (haveB1) *(bf16x8*)&Bs[ar1][aseg * 8] = pb1;
        }
    }
#pragma unroll
    for (int i = 0; i < 2; i++) {
#pragma unroll
        for (int ii = 0; ii < 4; ii++) {
            int row = row0 + wr + i * 16 + lq * 4 + ii;
#pragma unroll
            for (int j = 0; j < NT; j++) {
                int col = j * 16 + lm;
                myout[(size_t)row * N + col] = acc[i][j][ii];
            }
        }
    }
}

// ---------------- tiled causal conv (k=4) + silu -> uT only --------------
// z half untouched: scan reads z directly from xzb (resT eliminated, R16).
__global__ __launch_bounds__(256) void conv_silu_kernel(
        const unsigned short* __restrict__ xzb,
        const float* __restrict__ cw,
        const float* __restrict__ cb,
        float* __restrict__ uT) {
    __shared__ unsigned short s_xz[67][66];
    __shared__ float us[64][65];
    int tid = threadIdx.x;
    int d0 = blockIdx.x * 64, r0 = blockIdx.y * 64;
    bool atStart = (r0 & (L_SEQ - 1)) == 0;
    for (int idx = tid; idx < 67 * 64; idx += 256) {
        int rr = idx >> 6, cc2 = idx & 63;
        unsigned short v = 0;
        if (rr >= 3 || !atStart)
            v = xzb[(size_t)(r0 - 3 + rr) * (2 * D_INNER) + d0 + cc2];
        s_xz[rr][cc2] = v;
    }
    __syncthreads();
    int cc = tid & 63, ty = tid >> 6;
    const float* wp = cw + (size_t)(d0 + cc) * D_CONV;
    float w0 = wp[0], w1 = wp[1], w2 = wp[2], w3 = wp[3];
    float bb = cb[d0 + cc];
    for (int rr = ty; rr < 64; rr += 4) {
        float s = bb;
        s = fmaf(bf2f(s_xz[rr + 0][cc]), w0, s);
        s = fmaf(bf2f(s_xz[rr + 1][cc]), w1, s);
        s = fmaf(bf2f(s_xz[rr + 2][cc]), w2, s);
        s = fmaf(bf2f(s_xz[rr + 3][cc]), w3, s);
        us[rr][cc] = silu_f(s);
    }
    __syncthreads();
    int tx = tid & 63, dy = tid >> 6;
    for (int dd = dy; dd < 64; dd += 4)
        uT[(size_t)(d0 + dd) * ROWS + r0 + tx] = us[tx][dd];
}

// ---------------- chunk-parallel selective scan, adaptive re-chunk -------
// Gating z read DIRECTLY from xzb (6KB-strided gather; L2-absorbed) —
// replaces the resT copy. Bit-identical values.
__global__ __launch_bounds__(256) void scan_kernel(
        const float* __restrict__ deltaT,  // (D_INNER, ROWS)
        const float* __restrict__ uT,      // (D_INNER, ROWS)
        const float* __restrict__ xdbl,    // (ROWS, 80): [.,48:64]=B, [.,64:80]=C
        const unsigned short* __restrict__ xzb,   // (ROWS, 2*D_INNER); z at [.,D_INNER+d]
        const float* __restrict__ A_log,   // (D_INNER, 16) this layer
        const float* __restrict__ Dp,      // (D_INNER) this layer
        unsigned short* __restrict__ ygT) {// (D_INNER, ROWS) bf16 gated y
    int tid = threadIdx.x;
    int n = tid & 15, c = tid >> 4;
    int bd = blockIdx.x;
    int b = bd / D_INNER, d = bd - b * D_INNER;
    int row0 = b * L_SEQ;
    float a2 = -fast_exp(A_log[d * D_STATE + n]) * 1.44269504f;  // log2 domain
    float Dd = Dp[d];
    __shared__ float2 s_du[L_SEQ + 16];
    __shared__ float cs1[16][17];
    __shared__ float cs2[16][17];
    __shared__ float gmv[16];
    const float* dptr = deltaT + (size_t)d * ROWS + row0;
    const float* uptr = uT + (size_t)d * ROWS + row0;
    for (int e = tid; e < L_SEQ; e += 256)
        s_du[e + (e >> 6)] = make_float2(dptr[e], uptr[e]);
    __syncthreads();
    // ---- pass 1: 64-step chunk sums of dA (global l==0 excluded) ----
    {
        int l0 = c * 64, sb = l0 + c;
        bool notfirst = (c != 0);
        float sum = 0.f;
#pragma unroll 8
        for (int j = 0; j < 64; j++) {
            float dA = fmaxf(s_du[sb + j].x * a2, -28.8539008f);
            if (j > 0 || notfirst) sum += dA;
        }
        cs1[n][c] = sum;
    }
    __syncthreads();
    float cbase = 0.f;
    for (int cc = 0; cc < c; cc++) cbase += cs1[n][cc];
    float gm = cbase;
    gm = fmaxf(gm, __shfl_xor(gm, 1, 16));
    gm = fmaxf(gm, __shfl_xor(gm, 2, 16));
    gm = fmaxf(gm, __shfl_xor(gm, 4, 16));
    gm = fmaxf(gm, __shfl_xor(gm, 8, 16));
    if (n == 0) gmv[c] = gm;
    __syncthreads();
    int lc = 16;
    for (int cc = 1; cc < 16; cc++)
        if (gmv[cc] <= -150.0f) { lc = cc; break; }
    int clen = lc * 4;
    int l0b = c * clen;
    int lend = lc * 64;
    // ---- pass 1b: sub-chunk sums of dA ----
    {
        float sum = 0.f;
        for (int j = 0; j < clen; j++) {
            int l = l0b + j;
            float dA = fmaxf(s_du[l + (l >> 6)].x * a2, -28.8539008f);
            if (l > 0) sum += dA;
        }
        cs1[n][c] = sum;
    }
    __syncthreads();
    float cbase_b = 0.f;
    for (int cc = 0; cc < c; cc++) cbase_b += cs1[n][cc];
    // ---- pass 2b: sub-chunk P-term sums ----
    const float* xBbase = xdbl + (size_t)row0 * 80 + DT_RANK + n;
    {
        float Cacc = cbase_b, psum = 0.f;
        for (int j = 0; j < clen; j++) {
            int l = l0b + j;
            float2 du = s_du[l + (l >> 6)];
            float dA = fmaxf(du.x * a2, -28.8539008f);
            if (l > 0) Cacc += dA;
            float S = fast_exp2(Cacc);
            float r = fast_rcp(S + 1e-12f);
            psum = fmaf(du.x * du.y * xBbase[l * 80], r, psum);
        }
        cs2[n][c] = psum;
    }
    __syncthreads();
    float pbase = 0.f;
    for (int cc = 0; cc < c; cc++) pbase += cs2[n][cc];
    // ---- pass 3b: replay; n==0 writes raw y into s_du[.].x ----
    {
        float Cacc = cbase_b, P = pbase;
        for (int j = 0; j < clen; j++) {
            int l = l0b + j;
            float2 du = s_du[l + (l >> 6)];
            float dA = fmaxf(du.x * a2, -28.8539008f);
            if (l > 0) Cacc += dA;
            float S = fast_exp2(Cacc);
            float r = fast_rcp(S + 1e-12f);
            P = fmaf(du.x * du.y * xBbase[l * 80], r, P);
            float contrib = P * S * xBbase[l * 80 + 16];
            contrib += __shfl_xor(contrib, 1, 16);
            contrib += __shfl_xor(contrib, 2, 16);
            contrib += __shfl_xor(contrib, 4, 16);
            contrib += __shfl_xor(contrib, 8, 16);
            if (n == 0) s_du[l + (l >> 6)].x = contrib + du.y * Dd;
        }
    }
    __syncthreads();
    const unsigned short* zptr = xzb + (size_t)row0 * (2 * D_INNER) + D_INNER + d;
    unsigned short* yout = ygT + (size_t)d * ROWS + row0;
    for (int e = tid; e < L_SEQ; e += 256) {
        float2 v = s_du[e + (e >> 6)];
        float y = (e < lend) ? v.x : v.y * Dd;
        float res = bf2f(zptr[(size_t)e * (2 * D_INNER)]);
        yout[e] = f2bf(y * silu_f(res));
    }
}

extern "C" void kernel_launch(void* const* d_in, const int* in_sizes, int n_in,
                              void* d_out, int out_size, void* d_ws, size_t ws_size,
                              hipStream_t stream) {
    const int*   ids    = (const int*)d_in[0];
    const float* emb    = (const float*)d_in[1];
    const float* rms_w  = (const float*)d_in[2];
    const float* in_w   = (const float*)d_in[3];
    const float* conv_w = (const float*)d_in[4];
    const float* conv_b = (const float*)d_in[5];
    const float* xp_w   = (const float*)d_in[6];
    const float* dt_w   = (const float*)d_in[7];
    const float* dt_b   = (const float*)d_in[8];
    const float* A_log  = (const float*)d_in[9];
    const float* Dp     = (const float*)d_in[10];
    const float* out_w  = (const float*)d_in[11];
    const float* nf_w   = (const float*)d_in[12];
    const float* head_w = (const float*)d_in[13];
    float* out = (float*)d_out;

    // workspace layout (bytes) — total 77,766,656. No aliasing: xzb stays
    // live through scan (z read direct); ygT in its own slot; part standalone
    // sized for 24 splits.
    char* base = (char*)d_ws;
    float*          x      = (float*)(base + 0);                  //  6,291,456
    unsigned short* hb     = (unsigned short*)(base + 6291456);   //  3,145,728
    unsigned short* xzb    = (unsigned short*)(base + 9437184);   // 12,582,912
    float*          uT     = (float*)(base + 22020096);           // 12,582,912
    float*          xdbl   = (float*)(base + 34603008);           //    655,360
    unsigned short* xdblb  = (unsigned short*)(base + 35258368);  //    262,144
    float*          part   = (float*)(base + 35520512);           // 15,728,640 (24 splits)
    float*          deltaT = (float*)(base + 51249152);           // 12,582,912
    unsigned short* ygT    = (unsigned short*)(base + 63832064);  //  6,291,456
    unsigned short* wt_in  = (unsigned short*)(base + 70123520);  //  4,718,592
    unsigned short* wt_out = (unsigned short*)(base + 74842112);  //  2,359,296
    unsigned short* xpT    = (unsigned short*)(base + 77201408);  //    245,760
    unsigned short* dtwT   = (unsigned short*)(base + 77447168);  //    196,608
    unsigned short* headT  = (unsigned short*)(base + 77643776);  //    122,880

    embed_head_kernel<<<(ROWS * D_MODEL + N_MELS * D_MODEL + 255) / 256, 256, 0, stream>>>(
        ids, emb, x, head_w, headT);

    for (int i = 0; i < N_LAYER; i++) {
        const float* in_wi   = in_w + (size_t)i * D_MODEL * 2 * D_INNER;
        const float* conv_wi = conv_w + (size_t)i * D_INNER * D_CONV;
        const float* conv_bi = conv_b + (size_t)i * D_INNER;
        const float* xp_wi   = xp_w + (size_t)i * D_INNER * (DT_RANK + 2 * D_STATE);
        const float* dt_wi   = dt_w + (size_t)i * DT_RANK * D_INNER;
        const float* dt_bi   = dt_b + (size_t)i * D_INNER;
        const float* A_li    = A_log + (size_t)i * D_INNER * D_STATE;
        const float* Dpi     = Dp + (size_t)i * D_INNER;
        const float* out_wi  = out_w + (size_t)i * D_INNER * D_MODEL;
        const float* rms_wi  = rms_w + (size_t)i * D_MODEL;

        // weight prep + rmsnorm co-dispatched (independent works)
        prep_rms_kernel<<<4320 + ROWS, 256, 0, stream>>>(
            in_wi, out_wi, xp_wi, dt_wi, wt_in, wt_out, xpT, dtwT,
            x, rms_wi, hb);
        // xz = h @ in_proj_w : (2048,768)@(768,3072) -> bf16 [64x128, 768 blocks]
        mfma_gemm64<<<dim3(2 * D_INNER / 128, ROWS / 64), 256, 0, stream>>>(
            hb, wt_in, nullptr, nullptr, nullptr, xzb,
            ROWS, 2 * D_INNER, D_MODEL, 2 * D_INNER, 0, 0);
        // conv + silu -> uT (d-major f32) only
        conv_silu_kernel<<<dim3(D_INNER / 64, ROWS / 64), 256, 0, stream>>>(
            xzb, conv_wi, conv_bi, uT);
        // x_dbl = u @ x_proj_w (split-24, A transposed from uT) [384 blocks]
        mfma_skinny<true><<<dim3(ROWS / 128, NSPLIT), 256, 0, stream>>>(
            nullptr, uT, xpT, part, ROWS, D_INNER, D_INNER / NSPLIT);
        reduce_cvt_kernel<<<(ROWS * 80 + 255) / 256, 256, 0, stream>>>(
            part, xdbl, xdblb, NSPLIT);
        // deltaT = softplus(dt_w^T @ x_dbl^T + dt_b): [32x128, single K-iter]
        mfma_gemm32<false><<<dim3(ROWS / 128, D_INNER / 32), 256, 0, stream>>>(
            dtwT, xdblb, dt_bi, nullptr, deltaT, nullptr,
            D_INNER, ROWS, 64, ROWS, 1, 1);
        // scan + gate (z direct from xzb) -> ygT (d-major)
        scan_kernel<<<B_SZ * D_INNER, 256, 0, stream>>>(
            deltaT, uT, xdbl, xzb, A_li, Dpi, ygT);
        // x = yg @ out_proj_w + x : A staged transposed from ygT
        mfma_gemm32<true><<<dim3(D_MODEL / 128, ROWS / 32), 256, 0, stream>>>(
            ygT, wt_out, nullptr, x, x, nullptr,
            ROWS, D_MODEL, D_INNER, D_MODEL, 0, 0);
    }

    rmsnorm_kernel<<<ROWS, 256, 0, stream>>>(x, nf_w, hb);
    // out = h @ head_w : split-24 partials -> reduce (writes all of d_out)
    mfma_skinny<false><<<dim3(ROWS / 128, NSPLIT), 256, 0, stream>>>(
        hb, nullptr, headT, part, ROWS, D_MODEL, D_MODEL / NSPLIT);
    reduce_split_kernel<<<(ROWS * N_MELS + 255) / 256, 256, 0, stream>>>(
        part, out, ROWS * N_MELS, NSPLIT);
}